// Round 10
// baseline (548.247 us; speedup 1.0000x reference)
//
#include <hip/hip_runtime.h>
#include <stdint.h>

// Sizes: x [16,1,512,512] f32 binary; weight [1024,512] f32; out [16,1,1024,529] f32.
// pot[b,o,t'] = sum_tau K(w[o,i],tau) * x[b,i,t'+15-tau] + 12.8
// K via cumsum^2 of its Delta^2 (<=2 adjacent pairs after moving the universal onset tap
// to an exact per-(b,t) histogram); pairs scattered at spike positions into 4 ramp-planes
// (v2 applied with +1 shift at cumsum time). WTA depression uniform -> per-batch counter.
// R10: R9's b64 cells put 64 lanes on 16 bank-pair slots (avg 4-way, 305k conflict
// cyc/CU = 35% of wall). Split to 4 separate b32 planes (stride 571): 64 lanes spread
// over all 32 banks (avg 2/bank = free, m136). Second plane via ds offset:2284 imm.
// Tail: spikes+hist+taps fused into k_pre; pot-zero folded into k_argmax. 7->4 launches.

#define NB 16
#define NI 512
#define NT 512
#define NO 1024
#define TOUT 529
#define SCAP 96           // spike capacity per (b,i); max observed ~48
#define OTILE 4
#define PLEN 571          // plane length in floats
#define ROWF 2284         // 4 planes * 571 floats per o-row
#define DUST 564u         // dustbin cell (> max real e 560, < PLEN)
#define THETA_F 25.6f
#define BIAS_T 12.8f

// ---------- P1 merged: spikes | hist | taps, dispatched on blockIdx.x ----------
__global__ __launch_bounds__(256) void k_pre(const float* __restrict__ x,
                                             const float* __restrict__ weight,
                                             unsigned short* __restrict__ slist,
                                             unsigned int* __restrict__ spkw,
                                             unsigned int* __restrict__ counts,
                                             float* __restrict__ hg,
                                             float4* __restrict__ tap) {
    __shared__ __align__(16) char lsd[1024];
    const int bid = blockIdx.x;
    const int tid = threadIdx.x;
    if (bid < 2048) {                              // ---- spike lists (wave per row) ----
        unsigned short (*sls)[SCAP] = (unsigned short(*)[SCAP])lsd;   // 768 B
        int wq = tid >> 6, lane = tid & 63;
        int row = bid * 4 + wq;                    // row = b*512 + i
        const float* xr = x + (size_t)row * NT;
        for (int j = lane; j < SCAP; j += 64) sls[wq][j] = 0xFFFFu;
        int base = 0;
        for (int kk = 0; kk < 8; ++kk) {
            int t = kk * 64 + lane;
            bool pred = xr[t] > 0.5f;
            unsigned long long mask = __ballot(pred);
            int pre = __popcll(mask & ((1ull << lane) - 1ull));
            int pos = base + pre;
            if (pred && pos < SCAP) sls[wq][pos] = (unsigned short)t;
            base += __popcll(mask);
        }
        __syncthreads();
        if (lane < SCAP / 2) {                     // full list for cold path
            unsigned v = (unsigned)sls[wq][2 * lane] | ((unsigned)sls[wq][2 * lane + 1] << 16);
            ((unsigned int*)(slist + (size_t)row * SCAP))[lane] = v;
        }
        if (lane < 32)                             // packed (k, k+32) pair words
            spkw[(size_t)row * 32 + lane] = (unsigned)sls[wq][lane] | ((unsigned)sls[wq][lane + 32] << 16);
        if (lane == 0) counts[row] = (unsigned)min(base, SCAP);
    } else if (bid < 2176) {                       // ---- onset hist (race-free) ----
        float* hs = (float*)lsd;                   // 1024 B
        int bid2 = bid - 2048;
        int b = bid2 >> 3, seg = bid2 & 7;
        int t = seg * 64 + (tid & 63), isub = tid >> 6;
        const float* xb = x + (size_t)b * NI * NT + t;
        float s = 0.f;
        for (int i = isub * 128; i < isub * 128 + 128; ++i) s += xb[(size_t)i * NT];
        hs[tid] = s;
        __syncthreads();
        if (tid < 64)                              // small ints: exact in f32
            hg[b * NT + seg * 64 + tid] = (hs[tid] + hs[tid + 64]) + (hs[tid + 128] + hs[tid + 192]);
    } else {                                       // ---- taps, o-major ----
        int p = (bid - 2176) * 256 + tid;          // o = p>>9, i = p&511 (i fast: coalesced)
        int o = p >> 9, i = p & 511;
        float w = weight[o * NI + i];
        float b15 = 1.5f * w;
        float vA1 = 0.f, vA2 = 0.f, vB1 = 0.f, vB2 = 0.f;
        int posA = 2000, posB = 2000, state = 0;
        float Km1 = 0.f, Km2 = 0.f;
        for (int tau = 0; tau <= 49; ++tau) {
            float K = 0.f;
            if (tau <= 47) {
                float f = (float)tau * 0.0625f;
                float g = b15 - (float)tau * 0.03125f;
                K = fmaxf(0.f, fminf(f, g));
            }
            float d = (K - Km1) - (Km1 - Km2);
            if (tau == 1) d -= 0.0625f;            // onset -> histogram
            if (d != 0.f) {
                if (state == 0)      { posA = tau; vA1 = d; state = 1; }
                else if (state == 1) { if (tau == posA + 1) { vA2 = d; state = 2; }
                                       else { posB = tau; vB1 = d; state = 3; } }
                else if (state == 2) { posB = tau; vB1 = d; state = 3; }
                else if (state == 3) { if (tau == posB + 1) { vB2 = d; state = 4; } }
            }
            Km2 = Km1; Km1 = K;
        }
        size_t base = 2 * ((size_t)o * NI + i);
        tap[base]     = make_float4(vA1, vA2, __int_as_float(posA), 0.f);
        tap[base + 1] = make_float4(vB1, vB2, __int_as_float(posB), 0.f);
    }
}

// ---------- P3: wave-exclusive-row scatter + fused double cumsum^2 + pot write ----------
// Wave w owns o-row w (4 b32 planes, stride PLEN). Lane: k=lane>>1 spike slot,
// ramp=lane&1 pair slot. b32 RMWs: 64 lanes -> 32 banks (avg 2/bank = free).
#define PROC(TP, WV, CNT, IDX)                                                        \
    {                                                                                 \
        const int p = __float_as_int((TP).z);                                         \
        {                                                                             \
            unsigned e = min((unsigned)((int)((WV) & 0xFFFFu) + p), DUST);            \
            float* c = accw + e;                                                      \
            float a0 = c[0], a1 = c[PLEN];                                            \
            c[0] = a0 + (TP).x; c[PLEN] = a1 + (TP).y;                                \
        }                                                                             \
        if ((CNT) > 32u) {                                                            \
            unsigned e = min((unsigned)((int)((WV) >> 16) + p), DUST);                \
            float* c = accw + e;                                                      \
            float a0 = c[0], a1 = c[PLEN];                                            \
            c[0] = a0 + (TP).x; c[PLEN] = a1 + (TP).y;                                \
        }                                                                             \
        if ((CNT) > 64u) {                                                            \
            const unsigned short* sr = slist + (size_t)(b * NI + (IDX)) * SCAP;       \
            for (int kk = 64 + k; kk < (int)(CNT); kk += 32) {                        \
                unsigned e = min((unsigned)((int)sr[kk] + p), DUST);                  \
                float* c = accw + e;                                                  \
                float a0 = c[0], a1 = c[PLEN];                                        \
                c[0] = a0 + (TP).x; c[PLEN] = a1 + (TP).y;                            \
            }                                                                         \
        }                                                                             \
    }

__global__ __launch_bounds__(256, 4) void k_scatter(const unsigned short* __restrict__ slist,
                                                    const unsigned int* __restrict__ spkw,
                                                    const unsigned int* __restrict__ counts,
                                                    const float4* __restrict__ tap,
                                                    const float* __restrict__ hg,
                                                    float* __restrict__ pot) {
    __shared__ __align__(16) float acc[OTILE * ROWF];   // 36,544 B
    __shared__ double pub[512];                         // 4,096 B -> 40,640 total: 4 blk/CU
    const int o0 = blockIdx.x * OTILE;
    const int b  = blockIdx.y;
    const int tid = threadIdx.x;
    const int w = tid >> 6, lane = tid & 63;
    const int k = lane >> 1, ramp = lane & 1;

    for (int idx = tid; idx < OTILE * ROWF / 4; idx += 256)
        ((float4*)acc)[idx] = make_float4(0.f, 0.f, 0.f, 0.f);
    __syncthreads();

    float* accw = acc + w * ROWF + ramp * (2 * PLEN);   // my planes (v1 @0, v2 @PLEN)
    const unsigned int* wrow = spkw + (size_t)(b * NI) * 32 + k;
    const float4* trow = tap + 2 * (size_t)(o0 + w) * NI + ramp;
    const uint4* crow = (const uint4*)(counts + b * NI);

    // prefetch quad 0 (statically-named scalars -> registers; R8's arrays spilled)
    float4 ntA = trow[0], ntB = trow[2], ntC = trow[4], ntD = trow[6];
    unsigned nwA = wrow[0], nwB = wrow[32], nwC = wrow[64], nwD = wrow[96];
    uint4 ncc = crow[0];

    const int NIQ = NI / 4;
    for (int iq = 0; iq < NIQ; ++iq) {
        const float4 tA = ntA, tB = ntB, tC = ntC, tD = ntD;
        const unsigned wA = nwA, wB = nwB, wC = nwC, wD = nwD;
        const uint4 cc = ncc;
        if (iq + 1 < NIQ) {                        // prefetch next quad
            const float4* tb = trow + (size_t)(iq + 1) * 8;
            ntA = tb[0]; ntB = tb[2]; ntC = tb[4]; ntD = tb[6];
            const unsigned int* wb = wrow + (size_t)(iq + 1) * 128;
            nwA = wb[0]; nwB = wb[32]; nwC = wb[64]; nwD = wb[96];
            ncc = crow[iq + 1];
        }
        const int i0 = iq * 4;
        PROC(tA, wA, cc.x, i0)
        PROC(tB, wB, cc.y, i0 + 1)
        PROC(tC, wC, cc.z, i0 + 2)
        PROC(tD, wD, cc.w, i0 + 3)
    }
    __syncthreads();

    // ---- cumsum^2 (double): thread (oo=w, q=lane) owns cells [9q, 9q+9) ----
    // d[e] = P0[e] + P2[e] + P1[e-1] + P3[e-1] + hist[e-1]/16
    const int q = lane;
    const float* row = acc + w * ROWF;
    const float* hb = hg + b * NT;
    double dsv[9];
    double s1d = 0.0, s2d = 0.0;
#pragma unroll
    for (int r = 0; r < 9; ++r) {
        int e = q * 9 + r;
        double d = 0.0;
        if (e < PLEN) {
            d = (double)row[e] + (double)row[2 * PLEN + e];
            if (e >= 1) {
                d += (double)row[PLEN + e - 1] + (double)row[3 * PLEN + e - 1];
                if (e <= NT) d += 0.0625 * (double)hb[e - 1];
            }
        }
        dsv[r] = d; s1d += d; s2d += s1d;
    }
    pub[2 * tid] = s1d; pub[2 * tid + 1] = s2d;
    __syncthreads();
    if (tid < 4) {                                 // serial carry scan per o-row
        double c1 = 0.0, c2 = 0.0;
        for (int qq = 0; qq < 64; ++qq) {
            int j = (tid << 6) + qq;
            double S1 = pub[2 * j], S2 = pub[2 * j + 1];
            pub[2 * j] = c1; pub[2 * j + 1] = c2;
            c2 += 9.0 * c1 + S2;
            c1 += S1;
        }
    }
    __syncthreads();
    {
        const double C1 = pub[2 * tid], C2 = pub[2 * tid + 1];
        double a1 = 0.0, a2 = 0.0;
        float* rowW = acc + w * ROWF;              // results into P0
        double av = 0.0;
#pragma unroll
        for (int r = 0; r < 9; ++r) {
            a1 += dsv[r]; a2 += a1;
            int e = q * 9 + r;
            av = C2 + C1 * (double)(r + 1) + a2;
            if (e < PLEN) rowW[e] = (float)av;
        }
    }
    __syncthreads();
    for (int oo = 0; oo < OTILE; ++oo)             // coalesced pot write (t fastest)
        for (int t = tid; t < TOUT; t += 256)
            pot[((size_t)(b * NO + o0 + oo)) * TOUT + t] = acc[oo * ROWF + t + 15] + BIAS_T;
}

// ---------- P4: per-(b,t) argmax + exclusive-window pot zeroing ----------
__global__ __launch_bounds__(256) void k_argmax(float* __restrict__ pot,
                                                float* __restrict__ aval,
                                                unsigned short* __restrict__ aidx) {
    __shared__ float sv[4][64];
    __shared__ int   si[4][64];
    int b = blockIdx.y;
    int t0 = blockIdx.x * 64;
    int lane = threadIdx.x & 63, grp = threadIdx.x >> 6;
    int t = t0 + lane;
    bool valid = t < TOUT;
    float best = -1.f; int bidx = 0;
    if (valid) {
        for (int od = 0; od < 256; ++od) {         // ascending o + strict '>' => first max wins
            int o = grp * 256 + od;
            float v = pot[((size_t)(b * NO + o)) * TOUT + t];
            if (v > best) { best = v; bidx = o; }
        }
    }
    sv[grp][lane] = best; si[grp][lane] = bidx;
    __syncthreads();
    if (grp == 0 && valid) {
#pragma unroll
        for (int g = 1; g < 4; ++g) {
            float v = sv[g][lane];
            if (v > best) { best = v; bidx = si[g][lane]; }
        }
        aval[t * NB + b] = best;
        aidx[t * NB + b] = (unsigned short)bidx;
    }
    // zero this block's exclusive window [t0, t0+64) x all o (read above, pre-barrier)
    for (int idx = threadIdx.x; idx < NO * 64; idx += 256) {
        int o = idx >> 6, tt = idx & 63;
        int tz = t0 + tt;
        if (tz < TOUT) pot[((size_t)(b * NO + o)) * TOUT + tz] = 0.f;
    }
}

// ---------- P5: serial refractory scan (depression uniform across neurons) ----------
__global__ __launch_bounds__(256) void k_wta(const float* __restrict__ aval,
                                             const unsigned short* __restrict__ aidx,
                                             float* __restrict__ out) {
    __shared__ float lv[TOUT * NB];
    __shared__ unsigned short li[TOUT * NB];
    for (int idx = threadIdx.x; idx < TOUT * NB; idx += 256) { lv[idx] = aval[idx]; li[idx] = aidx[idx]; }
    __syncthreads();
    int b = threadIdx.x;
    if (b < NB) {
        int r = 0;
        for (int t = 0; t < TOUT; ++t) {
            float v = lv[t * NB + b];
            if (r == 0 && v > THETA_F) {
                int n = (int)li[t * NB + b];
                out[((size_t)(b * NO + n)) * TOUT + t] = 1.0f;
                r = 48;
            }
            r = max(r - 1, 0);
        }
    }
}

extern "C" void kernel_launch(void* const* d_in, const int* in_sizes, int n_in,
                              void* d_out, int out_size, void* d_ws, size_t ws_size,
                              hipStream_t stream) {
    const float* x      = (const float*)d_in[0];   // [16,1,512,512]
    const float* weight = (const float*)d_in[1];   // [1024,512]
    float* out = (float*)d_out;                    // [16,1,1024,529]
    char* ws = (char*)d_ws;
    // ws layout (~19.5 MB)
    unsigned short* slist  = (unsigned short*)(ws);            // 8192*96*2     = 1,572,864
    unsigned int*   spkw   = (unsigned int*)(ws + 1572864);    // 8192*32*4     = 1,048,576
    unsigned int*   counts = (unsigned int*)(ws + 2621440);    // 8192*4        = 32,768
    float4*         tap    = (float4*)(ws + 2654208);          // 1024*512*2*16 = 16,777,216
    float*          hg     = (float*)(ws + 19431424);          // 16*512*4      = 32,768
    float*          aval   = (float*)(ws + 19464192);          // 529*16*4      = 33,856
    unsigned short* aidx   = (unsigned short*)(ws + 19498048); // 529*16*2      = 16,928

    k_pre<<<4224, 256, 0, stream>>>(x, weight, slist, spkw, counts, hg, tap);
    k_scatter<<<dim3(NO / OTILE, NB), 256, 0, stream>>>(slist, spkw, counts, tap, hg, out);
    k_argmax<<<dim3(9, 16), 256, 0, stream>>>(out, aval, aidx);   // also zeros pot
    k_wta<<<1, 256, 0, stream>>>(aval, aidx, out);                // write spikes
}

// Round 11
// 521.192 us; speedup vs baseline: 1.0519x; 1.0519x over previous
//
#include <hip/hip_runtime.h>
#include <stdint.h>

// Sizes: x [16,1,512,512] f32 binary; weight [1024,512] f32; out [16,1,1024,529] f32.
// pot[b,o,t'] = sum_tau K(w[o,i],tau) * x[b,i,t'+15-tau] + 12.8
// K via cumsum^2 of its Delta^2 (<=2 adjacent pairs; universal onset tap -> exact
// per-(b,t) histogram). Pairs scattered at spike positions into a float4 cell
// (ramp0: .xy, ramp1: .zw; v2 gets +1 shift at cumsum). WTA depression uniform ->
// per-batch refractory counter.
// R11: R10 falsified the banking theory (random addrs conflict regardless of layout;
// b32 split just doubled instrs). Revert to R9 b64 cells + (a) exec-guard instead of
// dustbin clamp (idle lanes issue NO LDS op; tests same-addr-write serialization),
// (b) pre-scaled s*4/p*4 addressing, (c) uint4 spike words (1 VMEM/quad),
// (d) pot never materialized: per-block 4-o argmax -> u64 atomicMax keyed
// (orderable-val<<10 | 1023-o) -> exact lowest-o tie-break, order-independent.

#define NB 16
#define NI 512
#define NT 512
#define NO 1024
#define TOUT 529
#define SCAP 96           // spike capacity per (b,i); max observed ~48
#define OTILE 4
#define NCELL 562
#define E4LIM 2248u       // 562*4: guard bound on pre-scaled cell index
#define THETA_F 25.6f
#define BIAS_T 12.8f

// ---------- P1 merged: spikes | hist | taps, dispatched on blockIdx.x ----------
__global__ __launch_bounds__(256) void k_pre(const float* __restrict__ x,
                                             const float* __restrict__ weight,
                                             unsigned short* __restrict__ slist,
                                             unsigned int* __restrict__ spkw,
                                             unsigned int* __restrict__ counts,
                                             float* __restrict__ hg,
                                             float4* __restrict__ tap) {
    __shared__ __align__(16) char lsd[1024];
    const int bid = blockIdx.x;
    const int tid = threadIdx.x;
    if (bid < 2048) {                              // ---- spike lists (wave per row) ----
        unsigned short (*sls)[SCAP] = (unsigned short(*)[SCAP])lsd;   // 768 B
        int wq = tid >> 6, lane = tid & 63;
        int row = bid * 4 + wq;                    // row = b*512 + i
        const float* xr = x + (size_t)row * NT;
        for (int j = lane; j < SCAP; j += 64) sls[wq][j] = 0xFFFFu;
        int base = 0;
        for (int kk = 0; kk < 8; ++kk) {
            int t = kk * 64 + lane;
            bool pred = xr[t] > 0.5f;
            unsigned long long mask = __ballot(pred);
            int pre = __popcll(mask & ((1ull << lane) - 1ull));
            int pos = base + pre;
            if (pred && pos < SCAP) sls[wq][pos] = (unsigned short)t;
            base += __popcll(mask);
        }
        __syncthreads();
        if (lane < SCAP / 2) {                     // full list for cold path
            unsigned v = (unsigned)sls[wq][2 * lane] | ((unsigned)sls[wq][2 * lane + 1] << 16);
            ((unsigned int*)(slist + (size_t)row * SCAP))[lane] = v;
        }
        if (lane < 32) {                           // packed pre-scaled (4s_k | 4s_{k+32}<<16)
            unsigned a = min((unsigned)sls[wq][lane] * 4u, 0xFFFFu);
            unsigned c = min((unsigned)sls[wq][lane + 32] * 4u, 0xFFFFu);
            // layout: [(row>>2)*32 + k]*4 + (row&3)  -> one uint4 per (i-quad, k)
            spkw[(((size_t)(row >> 2)) * 32 + lane) * 4 + (row & 3)] = a | (c << 16);
        }
        if (lane == 0) counts[row] = (unsigned)min(base, SCAP);
    } else if (bid < 2176) {                       // ---- onset hist (race-free) ----
        float* hs = (float*)lsd;                   // 1024 B
        int bid2 = bid - 2048;
        int b = bid2 >> 3, seg = bid2 & 7;
        int t = seg * 64 + (tid & 63), isub = tid >> 6;
        const float* xb = x + (size_t)b * NI * NT + t;
        float s = 0.f;
        for (int i = isub * 128; i < isub * 128 + 128; ++i) s += xb[(size_t)i * NT];
        hs[tid] = s;
        __syncthreads();
        if (tid < 64)                              // small ints: exact in f32
            hg[b * NT + seg * 64 + tid] = (hs[tid] + hs[tid + 64]) + (hs[tid + 128] + hs[tid + 192]);
    } else {                                       // ---- taps, o-major, pos pre-scaled *4 ----
        int p = (bid - 2176) * 256 + tid;
        int o = p >> 9, i = p & 511;
        float w = weight[o * NI + i];
        float b15 = 1.5f * w;
        float vA1 = 0.f, vA2 = 0.f, vB1 = 0.f, vB2 = 0.f;
        int posA = 2000, posB = 2000, state = 0;
        float Km1 = 0.f, Km2 = 0.f;
        for (int tau = 0; tau <= 49; ++tau) {
            float K = 0.f;
            if (tau <= 47) {
                float f = (float)tau * 0.0625f;
                float g = b15 - (float)tau * 0.03125f;
                K = fmaxf(0.f, fminf(f, g));
            }
            float d = (K - Km1) - (Km1 - Km2);
            if (tau == 1) d -= 0.0625f;            // onset -> histogram
            if (d != 0.f) {
                if (state == 0)      { posA = tau; vA1 = d; state = 1; }
                else if (state == 1) { if (tau == posA + 1) { vA2 = d; state = 2; }
                                       else { posB = tau; vB1 = d; state = 3; } }
                else if (state == 2) { posB = tau; vB1 = d; state = 3; }
                else if (state == 3) { if (tau == posB + 1) { vB2 = d; state = 4; } }
            }
            Km2 = Km1; Km1 = K;
        }
        size_t base = 2 * ((size_t)o * NI + i);
        tap[base]     = make_float4(vA1, vA2, __int_as_float(posA * 4), 0.f);
        tap[base + 1] = make_float4(vB1, vB2, __int_as_float(posB * 4), 0.f);
    }
}

// ---------- P3: wave-exclusive-row scatter + cumsum^2 + argmax-key epilogue ----------
// Wave w owns o-row w (float4 cells: ramp0 .xy, ramp1 .zw). Lane: k=lane>>1 spike slot,
// ramp=lane&1. Guard e4<E4LIM exec-masks pads/sentinels/empty-pairs (no LDS op issued).
#define PROC(TP, WV, CNT, IDX)                                                        \
    {                                                                                 \
        const int p4 = __float_as_int((TP).z);                                        \
        {                                                                             \
            unsigned e4 = ((WV) & 0xFFFFu) + p4;                                      \
            if (e4 < E4LIM) {                                                         \
                float2* cell = (float2*)(accw + e4);                                  \
                float2 v = *cell; v.x += (TP).x; v.y += (TP).y; *cell = v;            \
            }                                                                         \
        }                                                                             \
        if ((CNT) > 32u) {                                                            \
            unsigned e4 = ((WV) >> 16) + p4;                                          \
            if (e4 < E4LIM) {                                                         \
                float2* cell = (float2*)(accw + e4);                                  \
                float2 v = *cell; v.x += (TP).x; v.y += (TP).y; *cell = v;            \
            }                                                                         \
        }                                                                             \
        if ((CNT) > 64u) {                                                            \
            const unsigned short* sr = slist + (size_t)(b * NI + (IDX)) * SCAP;       \
            for (int kk = 64 + k; kk < (int)(CNT); kk += 32) {                        \
                unsigned e4 = (unsigned)sr[kk] * 4u + p4;                             \
                if (e4 < E4LIM) {                                                     \
                    float2* cell = (float2*)(accw + e4);                              \
                    float2 v = *cell; v.x += (TP).x; v.y += (TP).y; *cell = v;        \
                }                                                                     \
            }                                                                         \
        }                                                                             \
    }

__global__ __launch_bounds__(256, 4) void k_scatter(const unsigned short* __restrict__ slist,
                                                    const unsigned int* __restrict__ spkw,
                                                    const unsigned int* __restrict__ counts,
                                                    const float4* __restrict__ tap,
                                                    const float* __restrict__ hg,
                                                    unsigned long long* __restrict__ akey) {
    __shared__ float4 acc[OTILE * NCELL];          // 35,968 B
    __shared__ double pub[512];                    // 4,096 B -> 40,064: 4 blk/CU
    const int o0 = blockIdx.x * OTILE;
    const int b  = blockIdx.y;
    const int tid = threadIdx.x;
    const int w = tid >> 6, lane = tid & 63;
    const int k = lane >> 1, ramp = lane & 1;

    for (int idx = tid; idx < OTILE * NCELL; idx += 256) acc[idx] = make_float4(0.f, 0.f, 0.f, 0.f);
    __syncthreads();

    float* accw = (float*)(acc + w * NCELL) + ramp * 2;
    const uint4* wrow = (const uint4*)spkw + (size_t)(b * 128) * 32 + k;
    const float4* trow = tap + 2 * (size_t)(o0 + w) * NI + ramp;
    const uint4* crow = (const uint4*)(counts + b * NI);

    // prefetch quad 0 (statically-named scalars only: R8's dynamic arrays spilled)
    float4 ntA = trow[0], ntB = trow[2], ntC = trow[4], ntD = trow[6];
    uint4 nwv = wrow[0];
    uint4 ncc = crow[0];

    const int NIQ = NI / 4;
    for (int iq = 0; iq < NIQ; ++iq) {
        const float4 tA = ntA, tB = ntB, tC = ntC, tD = ntD;
        const uint4 wv = nwv;
        const uint4 cc = ncc;
        if (iq + 1 < NIQ) {                        // prefetch next quad
            const float4* tb = trow + (size_t)(iq + 1) * 8;
            ntA = tb[0]; ntB = tb[2]; ntC = tb[4]; ntD = tb[6];
            nwv = wrow[(size_t)(iq + 1) * 32];
            ncc = crow[iq + 1];
        }
        const int i0 = iq * 4;
        PROC(tA, wv.x, cc.x, i0)
        PROC(tB, wv.y, cc.y, i0 + 1)
        PROC(tC, wv.z, cc.z, i0 + 2)
        PROC(tD, wv.w, cc.w, i0 + 3)
    }
    __syncthreads();

    // ---- cumsum^2 (double): thread (oo=w, q=lane) owns cells [9q, 9q+9) ----
    // d[e] = c[e].x + c[e].z + c[e-1].y + c[e-1].w + hist[e-1]/16
    const int q = lane;
    const float4* rowQ = acc + w * NCELL;
    const float* hb = hg + b * NT;
    double dsv[9];
    double s1d = 0.0, s2d = 0.0;
#pragma unroll
    for (int r = 0; r < 9; ++r) {
        int e = q * 9 + r;
        double d = 0.0;
        if (e < 561) {
            float4 c = rowQ[e];
            d = (double)c.x + (double)c.z;
            if (e >= 1) {
                float4 cm = rowQ[e - 1];
                d += (double)cm.y + (double)cm.w;
                if (e <= NT) d += 0.0625 * (double)hb[e - 1];
            }
        }
        dsv[r] = d; s1d += d; s2d += s1d;
    }
    pub[2 * tid] = s1d; pub[2 * tid + 1] = s2d;
    __syncthreads();
    if (tid < 4) {                                 // serial carry scan per o-row
        double c1 = 0.0, c2 = 0.0;
        for (int qq = 0; qq < 64; ++qq) {
            int j = (tid << 6) + qq;
            double S1 = pub[2 * j], S2 = pub[2 * j + 1];
            pub[2 * j] = c1; pub[2 * j + 1] = c2;
            c2 += 9.0 * c1 + S2;
            c1 += S1;
        }
    }
    __syncthreads();
    {
        const double C1 = pub[2 * tid], C2 = pub[2 * tid + 1];
        double a1 = 0.0, a2 = 0.0;
        float4* rowW = acc + w * NCELL;
#pragma unroll
        for (int r = 0; r < 9; ++r) {
            a1 += dsv[r]; a2 += a1;
            int e = q * 9 + r;
            if (e < 561) rowW[e].x = (float)(C2 + C1 * (double)(r + 1) + a2);
        }
    }
    __syncthreads();
    // ---- epilogue: block-local 4-o argmax per t -> u64 atomicMax key ----
    for (int t = tid; t < TOUT; t += 256) {
        float best = acc[t + 15].x; int bi = 0;
#pragma unroll
        for (int oo = 1; oo < OTILE; ++oo) {
            float v = acc[oo * NCELL + t + 15].x;
            if (v > best) { best = v; bi = oo; }   // ascending oo + strict > = lowest o
        }
        float val = best + BIAS_T;
        unsigned fb = __float_as_uint(val);
        unsigned k32 = (fb & 0x80000000u) ? ~fb : (fb | 0x80000000u);   // orderable
        unsigned long long key = ((unsigned long long)k32 << 10) | (unsigned)(1023 - (o0 + bi));
        atomicMax(&akey[t * NB + b], key);         // max val, tie -> lowest o; exact
    }
}

// ---------- P5: decode keys + serial refractory scan ----------
__global__ __launch_bounds__(256) void k_wta(const unsigned long long* __restrict__ akey,
                                             float* __restrict__ out) {
    __shared__ float lv[TOUT * NB];
    __shared__ unsigned short li[TOUT * NB];
    for (int idx = threadIdx.x; idx < TOUT * NB; idx += 256) {
        unsigned long long key = akey[idx];
        unsigned k32 = (unsigned)(key >> 10);
        unsigned fb = (k32 & 0x80000000u) ? (k32 & 0x7FFFFFFFu) : ~k32;
        lv[idx] = __uint_as_float(fb);
        li[idx] = (unsigned short)(1023u - (unsigned)(key & 1023u));
    }
    __syncthreads();
    int b = threadIdx.x;
    if (b < NB) {
        int r = 0;
        for (int t = 0; t < TOUT; ++t) {
            float v = lv[t * NB + b];
            if (r == 0 && v > THETA_F) {
                int n = (int)li[t * NB + b];
                out[((size_t)(b * NO + n)) * TOUT + t] = 1.0f;
                r = 48;
            }
            r = max(r - 1, 0);
        }
    }
}

extern "C" void kernel_launch(void* const* d_in, const int* in_sizes, int n_in,
                              void* d_out, int out_size, void* d_ws, size_t ws_size,
                              hipStream_t stream) {
    const float* x      = (const float*)d_in[0];   // [16,1,512,512]
    const float* weight = (const float*)d_in[1];   // [1024,512]
    float* out = (float*)d_out;                    // [16,1,1024,529]
    char* ws = (char*)d_ws;
    // ws layout (~19.5 MB)
    unsigned short* slist  = (unsigned short*)(ws);              // 8192*96*2     = 1,572,864
    unsigned int*   spkw   = (unsigned int*)(ws + 1572864);      // 2048*32*4*4   = 1,048,576
    unsigned int*   counts = (unsigned int*)(ws + 2621440);      // 8192*4        = 32,768
    float4*         tap    = (float4*)(ws + 2654208);            // 1024*512*2*16 = 16,777,216
    float*          hg     = (float*)(ws + 19431424);            // 16*512*4      = 32,768
    unsigned long long* akey = (unsigned long long*)(ws + 19464192); // 529*16*8  = 67,712

    k_pre<<<4224, 256, 0, stream>>>(x, weight, slist, spkw, counts, hg, tap);
    hipMemsetAsync(akey, 0, TOUT * NB * sizeof(unsigned long long), stream);
    hipMemsetAsync(d_out, 0, (size_t)out_size * sizeof(float), stream);
    k_scatter<<<dim3(NO / OTILE, NB), 256, 0, stream>>>(slist, spkw, counts, tap, hg, akey);
    k_wta<<<1, 256, 0, stream>>>(akey, out);
}